// Round 2
// baseline (1387.471 us; speedup 1.0000x reference)
//
#include <hip/hip_runtime.h>

#define NN 50000
#define NE 1600000
#define DD 64
#define NGRAPH 64
#define DOUT 32
#define DELTA_F 2.5749f
#define BN_EPS_F 1e-5f

// ---------------- init: zero counters / bn stats / pool ----------------
__global__ void k_init(int* __restrict__ counts, float* __restrict__ bnstat,
                       float* __restrict__ gpool) {
    int i = blockIdx.x * 256 + threadIdx.x;
    if (i < NN) counts[i] = 0;
    if (i < 384) bnstat[i] = 0.f;
    if (i < NGRAPH * DD) gpool[i] = 0.f;
}

// ---------------- CSR build ----------------
__global__ void k_count(const int* __restrict__ dst, int* __restrict__ counts) {
    int e = blockIdx.x * 256 + threadIdx.x;
    if (e < NE) atomicAdd(&counts[dst[e]], 1);
}

__global__ void k_scan_a(const int* __restrict__ counts, int* __restrict__ blockSums) {
    __shared__ int red[256];
    int tid = threadIdx.x;
    int gid = blockIdx.x * 256 + tid;
    int v = (gid < NN) ? counts[gid] : 0;
    red[tid] = v;
    __syncthreads();
    for (int s = 128; s > 0; s >>= 1) {
        if (tid < s) red[tid] += red[tid + s];
        __syncthreads();
    }
    if (tid == 0) blockSums[blockIdx.x] = red[0];
}

__global__ void k_scan_b(const int* __restrict__ blockSums, int* __restrict__ blockBase) {
    __shared__ int sh[256];
    int tid = threadIdx.x;
    int v = (tid < 196) ? blockSums[tid] : 0;
    sh[tid] = v;
    __syncthreads();
    for (int off = 1; off < 256; off <<= 1) {
        int t = (tid >= off) ? sh[tid - off] : 0;
        __syncthreads();
        sh[tid] += t;
        __syncthreads();
    }
    blockBase[tid] = sh[tid] - v;  // exclusive
}

__global__ void k_scan_c(const int* __restrict__ counts, const int* __restrict__ blockBase,
                         int* __restrict__ row_ptr, int* __restrict__ cursor) {
    __shared__ int sh[256];
    int tid = threadIdx.x;
    int gid = blockIdx.x * 256 + tid;
    int v = (gid < NN) ? counts[gid] : 0;
    sh[tid] = v;
    __syncthreads();
    for (int off = 1; off < 256; off <<= 1) {
        int t = (tid >= off) ? sh[tid - off] : 0;
        __syncthreads();
        sh[tid] += t;
        __syncthreads();
    }
    int excl = blockBase[blockIdx.x] + sh[tid] - v;
    if (gid <= NN) {
        row_ptr[gid] = excl;
        if (gid < NN) cursor[gid] = excl;
    }
}

__global__ void k_fill(const int* __restrict__ src, const int* __restrict__ dst,
                       int* __restrict__ cursor, int* __restrict__ csr_src) {
    int e = blockIdx.x * 256 + threadIdx.x;
    if (e < NE) {
        int d = dst[e];
        int pos = atomicAdd(&cursor[d], 1);
        csr_src[pos] = src[e];
    }
}

// ---------------- per-node aggregation: sum/max/mean/var ----------------
__global__ __launch_bounds__(256) void k_agg(const float* __restrict__ X,
                                             const int* __restrict__ row_ptr,
                                             const int* __restrict__ csr_src,
                                             float* __restrict__ aggr) {
    int wave = threadIdx.x >> 6;
    int lane = threadIdx.x & 63;
    int node = blockIdx.x * 4 + wave;
    if (node >= NN) return;
    int beg = row_ptr[node], end = row_ptr[node + 1];
    float s = 0.f, sq = 0.f, mx = -3.402823466e38f;
    for (int e = beg; e < end; ++e) {
        int sv = csr_src[e];
        float v = X[sv * DD + lane];
        s += v;
        sq += v * v;
        mx = fmaxf(mx, v);
    }
    float c = (float)(end - beg);
    float mean = s / c;
    float var = fmaxf(sq / c - mean * mean, 0.f);
    float* ag = aggr + node * 256;
    ag[lane] = s;
    ag[64 + lane] = mx;
    ag[128 + lane] = mean;
    ag[192 + lane] = var;
}

// ---------------- transpose mlp weights (f32 [64,768] -> f32 [3 chunks][k][o]) ----------------
__global__ void k_wt(const float* __restrict__ w0, const float* __restrict__ w1,
                     const float* __restrict__ w2, float* __restrict__ Wt) {
    int i = blockIdx.x * 256 + threadIdx.x;  // < 3*49152
    if (i >= 3 * 49152) return;
    int l = i / 49152, r = i % 49152;
    const float* w = (l == 0) ? w0 : ((l == 1) ? w1 : w2);
    int o = r / 768, kk = r % 768;
    int c = kk >> 8, k = kk & 255;
    Wt[l * 49152 + c * 16384 + k * 64 + o] = w[r];
}

// ---------------- fused: a = comb@mlpW^T + b ; h = x+a ; Lin2(relu(Lin1(h))) ; relu ; BN partials ----------------
__global__ __launch_bounds__(256) void k_mlp(
    const float* __restrict__ X, const float* __restrict__ aggr,
    const float* __restrict__ Wt, const float* __restrict__ mlp_b,
    const float* __restrict__ W1, const float* __restrict__ b1,
    const float* __restrict__ W2, const float* __restrict__ b2,
    const int* __restrict__ row_ptr,
    float* __restrict__ Y, float* __restrict__ bnstat) {
    // LDS plan (floats):
    //   phase1: As[64][130] at [0, 8320)
    //   phase2: hs/ts/ys [64][65] at [0,4160) ; w1t [64][65] at [4160,8320) ; w2t at [8320,12480)
    //   biases: mbias@12480, b1s@12544, b2s@12608, degs@12672   (total 12736 floats = 49.75 KB)
    __shared__ float lds[12736];
    float* const w1t = lds + 4160;
    float* const w2t = lds + 8320;
    float* const mbias = lds + 12480;
    float* const b1s = lds + 12544;
    float* const b2s = lds + 12608;
    float* const degs = lds + 12672;

    const int tid = threadIdx.x;
    const int node0 = blockIdx.x * 64;

    if (tid < 64) {
        mbias[tid] = mlp_b[tid];
        b1s[tid] = b1[tid];
        b2s[tid] = b2[tid];
        int node = node0 + tid;
        degs[tid] = (node < NN) ? (float)(row_ptr[node + 1] - row_ptr[node]) : 1.f;
    }

    const int tx = tid & 15, ty = tid >> 4;
    const int o0 = tx * 4, n0 = ty * 4;

    float acc0[16], acc1[16], acc2[16];
#pragma unroll
    for (int i = 0; i < 16; ++i) { acc0[i] = 0.f; acc1[i] = 0.f; acc2[i] = 0.f; }

    const float* Wc0 = Wt;
    const float* Wc1 = Wt + 16384;
    const float* Wc2 = Wt + 32768;

    for (int half = 0; half < 2; ++half) {
        __syncthreads();
        for (int i = tid; i < 8192; i += 256) {
            int n = i >> 7, k = i & 127;
            int node = node0 + n;
            lds[n * 130 + k] = (node < NN) ? aggr[node * 256 + half * 128 + k] : 0.f;
        }
        __syncthreads();
        const int kb = half * 128;
#pragma unroll 2
        for (int k = 0; k < 128; ++k) {
            float a[4];
#pragma unroll
            for (int ni = 0; ni < 4; ++ni) a[ni] = lds[(n0 + ni) * 130 + k];
            const float4 w0 = *(const float4*)(Wc0 + (kb + k) * 64 + o0);
            const float4 w1v = *(const float4*)(Wc1 + (kb + k) * 64 + o0);
            const float4 w2v = *(const float4*)(Wc2 + (kb + k) * 64 + o0);
#pragma unroll
            for (int ni = 0; ni < 4; ++ni) {
                acc0[ni * 4 + 0] += a[ni] * w0.x;  acc0[ni * 4 + 1] += a[ni] * w0.y;
                acc0[ni * 4 + 2] += a[ni] * w0.z;  acc0[ni * 4 + 3] += a[ni] * w0.w;
                acc1[ni * 4 + 0] += a[ni] * w1v.x; acc1[ni * 4 + 1] += a[ni] * w1v.y;
                acc1[ni * 4 + 2] += a[ni] * w1v.z; acc1[ni * 4 + 3] += a[ni] * w1v.w;
                acc2[ni * 4 + 0] += a[ni] * w2v.x; acc2[ni * 4 + 1] += a[ni] * w2v.y;
                acc2[ni * 4 + 2] += a[ni] * w2v.z; acc2[ni * 4 + 3] += a[ni] * w2v.w;
            }
        }
    }
    __syncthreads();  // done reading As region

    // load transposed W1/W2 into LDS; compute h = x + a and stash in [0,4160)
    for (int i = tid; i < 4096; i += 256) {
        int o = i >> 6, j = i & 63;
        w1t[j * 65 + o] = W1[i];
        w2t[j * 65 + o] = W2[i];
    }
#pragma unroll
    for (int ni = 0; ni < 4; ++ni) {
        int n = n0 + ni;
        int node = node0 + n;
        float dg = degs[n];
        float c1 = dg * (1.0f / DELTA_F);
        float c2 = DELTA_F / dg;
        float4 xv = make_float4(0.f, 0.f, 0.f, 0.f);
        if (node < NN) xv = *(const float4*)(X + node * DD + o0);
        lds[n * 65 + o0 + 0] = xv.x + acc0[ni * 4 + 0] + c1 * acc1[ni * 4 + 0] + c2 * acc2[ni * 4 + 0] + mbias[o0 + 0];
        lds[n * 65 + o0 + 1] = xv.y + acc0[ni * 4 + 1] + c1 * acc1[ni * 4 + 1] + c2 * acc2[ni * 4 + 1] + mbias[o0 + 1];
        lds[n * 65 + o0 + 2] = xv.z + acc0[ni * 4 + 2] + c1 * acc1[ni * 4 + 2] + c2 * acc2[ni * 4 + 2] + mbias[o0 + 2];
        lds[n * 65 + o0 + 3] = xv.w + acc0[ni * 4 + 3] + c1 * acc1[ni * 4 + 3] + c2 * acc2[ni * 4 + 3] + mbias[o0 + 3];
    }
    __syncthreads();

    // Lin1 (into registers)
    float l1[16];
#pragma unroll
    for (int i = 0; i < 16; ++i) l1[i] = 0.f;
    for (int j = 0; j < 64; ++j) {
        float wv0 = w1t[j * 65 + o0 + 0], wv1 = w1t[j * 65 + o0 + 1];
        float wv2 = w1t[j * 65 + o0 + 2], wv3 = w1t[j * 65 + o0 + 3];
#pragma unroll
        for (int ni = 0; ni < 4; ++ni) {
            float a = lds[(n0 + ni) * 65 + j];
            l1[ni * 4 + 0] += a * wv0; l1[ni * 4 + 1] += a * wv1;
            l1[ni * 4 + 2] += a * wv2; l1[ni * 4 + 3] += a * wv3;
        }
    }
    __syncthreads();  // all hs reads done; reuse region for t
#pragma unroll
    for (int ni = 0; ni < 4; ++ni)
#pragma unroll
        for (int oi = 0; oi < 4; ++oi)
            lds[(n0 + ni) * 65 + o0 + oi] = fmaxf(l1[ni * 4 + oi] + b1s[o0 + oi], 0.f);
    __syncthreads();

    // Lin2 + outer relu
    float l2[16];
#pragma unroll
    for (int i = 0; i < 16; ++i) l2[i] = 0.f;
    for (int j = 0; j < 64; ++j) {
        float wv0 = w2t[j * 65 + o0 + 0], wv1 = w2t[j * 65 + o0 + 1];
        float wv2 = w2t[j * 65 + o0 + 2], wv3 = w2t[j * 65 + o0 + 3];
#pragma unroll
        for (int ni = 0; ni < 4; ++ni) {
            float a = lds[(n0 + ni) * 65 + j];
            l2[ni * 4 + 0] += a * wv0; l2[ni * 4 + 1] += a * wv1;
            l2[ni * 4 + 2] += a * wv2; l2[ni * 4 + 3] += a * wv3;
        }
    }
    __syncthreads();  // all t reads done; reuse region for y
#pragma unroll
    for (int ni = 0; ni < 4; ++ni) {
        int node = node0 + n0 + ni;
        float4 yv;
        yv.x = fmaxf(l2[ni * 4 + 0] + b2s[o0 + 0], 0.f);
        yv.y = fmaxf(l2[ni * 4 + 1] + b2s[o0 + 1], 0.f);
        yv.z = fmaxf(l2[ni * 4 + 2] + b2s[o0 + 2], 0.f);
        yv.w = fmaxf(l2[ni * 4 + 3] + b2s[o0 + 3], 0.f);
        if (node < NN) *(float4*)(Y + node * DD + o0) = yv;
        lds[(n0 + ni) * 65 + o0 + 0] = yv.x;
        lds[(n0 + ni) * 65 + o0 + 1] = yv.y;
        lds[(n0 + ni) * 65 + o0 + 2] = yv.z;
        lds[(n0 + ni) * 65 + o0 + 3] = yv.w;
    }
    __syncthreads();

    // BN partial sums for this tile
    if (tid < 64) {
        float s = 0.f, sq = 0.f;
        int lim = NN - node0;
        if (lim > 64) lim = 64;
        for (int n = 0; n < lim; ++n) {
            float v = lds[n * 65 + tid];
            s += v;
            sq += v * v;
        }
        atomicAdd(&bnstat[tid], s);
        atomicAdd(&bnstat[64 + tid], sq);
    }
}

// ---------------- BN apply ----------------
__global__ void k_bnapply(const float* __restrict__ Y, const float* __restrict__ bnstat,
                          const float* __restrict__ g, const float* __restrict__ b,
                          float* __restrict__ XO) {
    int i = blockIdx.x * 256 + threadIdx.x;
    if (i >= NN * DD) return;
    int f = i & 63;
    float mean = bnstat[f] * (1.f / NN);
    float var = bnstat[64 + f] * (1.f / NN) - mean * mean;
    var = fmaxf(var, 0.f);
    float inv = rsqrtf(var + BN_EPS_F);
    XO[i] = (Y[i] - mean) * inv * g[f] + b[f];
}

// ---------------- global add pool ----------------
__global__ void k_pool(const float* __restrict__ XB, const int* __restrict__ batch,
                       float* __restrict__ gpool) {
    int i = blockIdx.x * 256 + threadIdx.x;
    if (i >= NN * DD) return;
    int n = i >> 6, f = i & 63;
    atomicAdd(&gpool[batch[n] * DD + f], XB[i]);
}

// ---------------- head: fc1+relu, fc2, log_softmax ----------------
__global__ __launch_bounds__(256) void k_head(const float* __restrict__ gpool,
                                              const float* __restrict__ fc1W, const float* __restrict__ fc1b,
                                              const float* __restrict__ fc2W, const float* __restrict__ fc2b,
                                              float* __restrict__ out) {
    // LDS overlay plan (floats): total 12576 = 50.3 KB
    //  phase1: gs[4096]@0 | w1t[4160]@4096 | z1s[4160]@8256 | b1s[64]@12416 | b2s[32]@12480
    //  phase2: w2t[2112]@0 (overlays gs) | z2s[2112]@4096 (overlays w1t) | z1s persists
    __shared__ float sh[12576];
    float* const gs = sh;
    float* const w1t = sh + 4096;
    float* const z1s = sh + 8256;
    float* const b1s = sh + 12416;
    float* const b2s = sh + 12480;
    float* const w2t = sh;
    float* const z2s = sh + 4096;

    int tid = threadIdx.x;
    for (int i = tid; i < 4096; i += 256) {
        gs[i] = gpool[i];
        int o = i >> 6, j = i & 63;
        w1t[j * 65 + o] = fc1W[i];
    }
    if (tid < 64) b1s[tid] = fc1b[tid];
    if (tid < 32) b2s[tid] = fc2b[tid];
    __syncthreads();
    {
        int tx = tid & 15, ty = tid >> 4, o0 = tx * 4, g0 = ty * 4;
        float acc[16];
#pragma unroll
        for (int i = 0; i < 16; ++i) acc[i] = 0.f;
        for (int j = 0; j < 64; ++j) {
            float w0 = w1t[j * 65 + o0 + 0], w1 = w1t[j * 65 + o0 + 1];
            float w2 = w1t[j * 65 + o0 + 2], w3 = w1t[j * 65 + o0 + 3];
#pragma unroll
            for (int gi = 0; gi < 4; ++gi) {
                float a = gs[(g0 + gi) * 64 + j];
                acc[gi * 4 + 0] += a * w0; acc[gi * 4 + 1] += a * w1;
                acc[gi * 4 + 2] += a * w2; acc[gi * 4 + 3] += a * w3;
            }
        }
        __syncthreads();  // everyone done reading gs/w1t before overlay
#pragma unroll
        for (int gi = 0; gi < 4; ++gi)
#pragma unroll
            for (int oi = 0; oi < 4; ++oi)
                z1s[(g0 + gi) * 65 + o0 + oi] = fmaxf(acc[gi * 4 + oi] + b1s[o0 + oi], 0.f);
    }
    // load w2t into the (dead) gs region
    for (int i = tid; i < 2048; i += 256) {
        int o = i >> 6, j = i & 63;
        w2t[j * 33 + o] = fc2W[i];
    }
    __syncthreads();
    {
        int tx = tid & 7, ty = tid >> 3, o0 = tx * 4, g0 = ty * 2;
        float acc[8];
#pragma unroll
        for (int i = 0; i < 8; ++i) acc[i] = 0.f;
        for (int j = 0; j < 64; ++j) {
            float w0 = w2t[j * 33 + o0 + 0], w1 = w2t[j * 33 + o0 + 1];
            float w2 = w2t[j * 33 + o0 + 2], w3 = w2t[j * 33 + o0 + 3];
            float a0 = z1s[(g0 + 0) * 65 + j];
            float a1 = z1s[(g0 + 1) * 65 + j];
            acc[0] += a0 * w0; acc[1] += a0 * w1; acc[2] += a0 * w2; acc[3] += a0 * w3;
            acc[4] += a1 * w0; acc[5] += a1 * w1; acc[6] += a1 * w2; acc[7] += a1 * w3;
        }
#pragma unroll
        for (int gi = 0; gi < 2; ++gi)
#pragma unroll
            for (int oi = 0; oi < 4; ++oi)
                z2s[(g0 + gi) * 33 + o0 + oi] = acc[gi * 4 + oi] + b2s[o0 + oi];
    }
    __syncthreads();
    if (tid < 64) {
        float m = -3.402823466e38f;
        for (int c = 0; c < DOUT; ++c) m = fmaxf(m, z2s[tid * 33 + c]);
        float s = 0.f;
        for (int c = 0; c < DOUT; ++c) s += expf(z2s[tid * 33 + c] - m);
        float lse = m + logf(s);
        for (int c = 0; c < DOUT; ++c)
            out[tid * DOUT + c] = z2s[tid * 33 + c] - lse;
    }
}

extern "C" void kernel_launch(void* const* d_in, const int* in_sizes, int n_in,
                              void* d_out, int out_size, void* d_ws, size_t ws_size,
                              hipStream_t stream) {
    const float* x = (const float*)d_in[0];
    const int* ei = (const int*)d_in[1];
    const int* src = ei;
    const int* dst = ei + NE;
    const int* batch = (const int*)d_in[2];
    const float *mlpW[3], *mlpB[3], *w1[3], *bb1[3], *w2[3], *bb2[3], *bng[3], *bnb[3];
    for (int l = 0; l < 3; ++l) {
        mlpW[l] = (const float*)d_in[3 + 6 * l];
        mlpB[l] = (const float*)d_in[4 + 6 * l];
        w1[l]   = (const float*)d_in[5 + 6 * l];
        bb1[l]  = (const float*)d_in[6 + 6 * l];
        w2[l]   = (const float*)d_in[7 + 6 * l];
        bb2[l]  = (const float*)d_in[8 + 6 * l];
        bng[l]  = (const float*)d_in[21 + 2 * l];
        bnb[l]  = (const float*)d_in[22 + 2 * l];
    }
    const float* fc1W = (const float*)d_in[27];
    const float* fc1b = (const float*)d_in[28];
    const float* fc2W = (const float*)d_in[29];
    const float* fc2b = (const float*)d_in[30];
    float* out = (float*)d_out;

    char* ws = (char*)d_ws;
    size_t off = 0;
    auto alloc = [&](size_t bytes) -> void* {
        void* p = ws + off;
        off = (off + bytes + 511) & ~(size_t)511;
        return p;
    };
    int* counts    = (int*)alloc((size_t)NN * 4);
    int* row_ptr   = (int*)alloc((size_t)(NN + 1) * 4);
    int* cursor    = (int*)alloc((size_t)NN * 4);
    int* blockSums = (int*)alloc(256 * 4);
    int* blockBase = (int*)alloc(256 * 4);
    int* csr_src   = (int*)alloc((size_t)NE * 4);
    float* XB      = (float*)alloc((size_t)NN * DD * 4);
    float* Yb      = (float*)alloc((size_t)NN * DD * 4);
    float* aggr    = (float*)alloc((size_t)NN * 256 * 4);
    float* Wt      = (float*)alloc((size_t)3 * 49152 * 4);
    float* bnstat  = (float*)alloc(384 * 4);
    float* gpool   = (float*)alloc((size_t)NGRAPH * DD * 4);
    (void)ws_size; (void)in_sizes; (void)n_in; (void)out_size;

    k_init<<<196, 256, 0, stream>>>(counts, bnstat, gpool);
    k_count<<<6250, 256, 0, stream>>>(dst, counts);
    k_scan_a<<<196, 256, 0, stream>>>(counts, blockSums);
    k_scan_b<<<1, 256, 0, stream>>>(blockSums, blockBase);
    k_scan_c<<<196, 256, 0, stream>>>(counts, blockBase, row_ptr, cursor);
    k_fill<<<6250, 256, 0, stream>>>(src, dst, cursor, csr_src);
    k_wt<<<576, 256, 0, stream>>>(mlpW[0], mlpW[1], mlpW[2], Wt);

    const float* Xin = x;
    for (int l = 0; l < 3; ++l) {
        k_agg<<<12500, 256, 0, stream>>>(Xin, row_ptr, csr_src, aggr);
        k_mlp<<<782, 256, 0, stream>>>(Xin, aggr, Wt + (size_t)l * 49152, mlpB[l],
                                       w1[l], bb1[l], w2[l], bb2[l], row_ptr,
                                       Yb, bnstat + l * 128);
        k_bnapply<<<12500, 256, 0, stream>>>(Yb, bnstat + l * 128, bng[l], bnb[l], XB);
        Xin = XB;
    }
    k_pool<<<12500, 256, 0, stream>>>(XB, batch, gpool);
    k_head<<<1, 256, 0, stream>>>(gpool, fc1W, fc1b, fc2W, fc2b, out);
}